// Round 1
// baseline (408.120 us; speedup 1.0000x reference)
//
#include <hip/hip_runtime.h>
#include <math.h>

#define TS   32      // tile side
#define PT   36      // padded tile side
#define NPIX 1024    // pixels per tile
#define DF   72      // feature dim: 3 ch * 24 non-center offsets
#define NBLK 64      // rows per workgroup
#define MBLK 64      // cols per m-block
#define IMH  320
#define IMW  320
#define NTW  10      // tiles per image row

__global__ __launch_bounds__(256, 2)
void nlm_kernel(const float* __restrict__ img, float* __restrict__ out)
{
    __shared__ float P[3][PT][PT];                     // padded tile, 15552 B
    __shared__ float sqf[NPIX];                        // |feature|^2 per pixel
    __shared__ __align__(16) float An[DF][NBLK];       // A features, k-major
    __shared__ __align__(16) float Bm[DF][MBLK];       // B features, k-major

    const int tid  = threadIdx.x;
    const int tile = blockIdx.y;          // 0..99
    const int n0   = blockIdx.x * NBLK;   // row block base
    const int by   = (tile / NTW) * TS;
    const int bx   = (tile % NTW) * TS;

    // ---- stage padded tile (replicate-pad per tile, like jnp.pad mode='edge')
    for (int idx = tid; idx < 3 * PT * PT; idx += 256) {
        int c   = idx / (PT * PT);
        int rem = idx - c * (PT * PT);
        int y   = rem / PT;
        int x   = rem - y * PT;
        int iy  = min(max(y - 2, 0), TS - 1);
        int ix  = min(max(x - 2, 0), TS - 1);
        P[c][y][x] = img[(c * IMH + by + iy) * IMW + bx + ix];
    }
    __syncthreads();

    // ---- squared feature norms for all 1024 pixels
    for (int m = tid; m < NPIX; m += 256) {
        int my = m >> 5, mx = m & 31;
        float s = 0.f;
        #pragma unroll
        for (int k = 0; k < 25; ++k) {
            if (k == 12) continue;          // skip center
            int i = k / 5, j = k - (k / 5) * 5;
            float v0 = P[0][my + i][mx + j];
            float v1 = P[1][my + i][mx + j];
            float v2 = P[2][my + i][mx + j];
            s = fmaf(v0, v0, s);
            s = fmaf(v1, v1, s);
            s = fmaf(v2, v2, s);
        }
        sqf[m] = s;
    }

    // ---- stage A features (this block's 64 rows), k-major for float4 GEMM reads
    for (int idx = tid; idx < DF * NBLK; idx += 256) {
        int f  = idx >> 6;          // 0..71
        int nn = idx & 63;
        int n  = n0 + nn;
        int c  = f / 24;
        int o  = f - c * 24;
        int k  = o + (o >= 12);
        int i  = k / 5, j = k - (k / 5) * 5;
        An[f][nn] = P[c][(n >> 5) + i][(n & 31) + j];
    }
    __syncthreads();

    const int r  = tid >> 4;   // row group 0..15 -> rows 4r..4r+3
    const int cg = tid & 15;   // col group 0..15 -> cols 4cg..4cg+3

    float sqn[4];
    float rowsum[4] = {0.f, 0.f, 0.f, 0.f};
    float oacc[4][3] = {};
    #pragma unroll
    for (int i = 0; i < 4; ++i) sqn[i] = sqf[n0 + 4 * r + i];

    for (int mb = 0; mb < NPIX / MBLK; ++mb) {
        const int m0 = mb * MBLK;

        // stage B features for this 64-col block
        for (int idx = tid; idx < DF * MBLK; idx += 256) {
            int f  = idx >> 6;
            int mm = idx & 63;
            int m  = m0 + mm;
            int c  = f / 24;
            int o  = f - c * 24;
            int k  = o + (o >= 12);
            int i  = k / 5, j = k - (k / 5) * 5;
            Bm[f][mm] = P[c][(m >> 5) + i][(m & 31) + j];
        }
        __syncthreads();

        // 4x4 register-blocked fp32 GEMM over K=72
        float acc[4][4] = {};
        #pragma unroll 8
        for (int k = 0; k < DF; ++k) {
            float4 a4 = *(const float4*)&An[k][4 * r];
            float4 b4 = *(const float4*)&Bm[k][4 * cg];
            float av[4] = {a4.x, a4.y, a4.z, a4.w};
            float bv[4] = {b4.x, b4.y, b4.z, b4.w};
            #pragma unroll
            for (int i = 0; i < 4; ++i)
                #pragma unroll
                for (int j = 0; j < 4; ++j)
                    acc[i][j] = fmaf(av[i], bv[j], acc[i][j]);
        }

        // fused epilogue: density, rowsum, weighted pixel accumulation
        #pragma unroll
        for (int j = 0; j < 4; ++j) {
            int m = m0 + 4 * cg + j;
            float sm = sqf[m];
            int my = m >> 5, mx = m & 31;
            float y0 = P[0][my + 2][mx + 2];
            float y1 = P[1][my + 2][mx + 2];
            float y2 = P[2][my + 2][mx + 2];
            #pragma unroll
            for (int i = 0; i < 4; ++i) {
                int n = n0 + 4 * r + i;
                float d2 = fmaxf(sqn[i] + sm - 2.f * acc[i][j], 0.f);
                float dens = __expf(-sqrtf(d2));
                if (m == n) dens = 0.f;     // diagonal excluded
                rowsum[i] += dens;
                oacc[i][0] = fmaf(dens, y0, oacc[i][0]);
                oacc[i][1] = fmaf(dens, y1, oacc[i][1]);
                oacc[i][2] = fmaf(dens, y2, oacc[i][2]);
            }
        }
        __syncthreads();   // before next Bm overwrite
    }

    // ---- reduce across the 16 col-group lanes (contiguous within a wave)
    #pragma unroll
    for (int mask = 1; mask < 16; mask <<= 1) {
        #pragma unroll
        for (int i = 0; i < 4; ++i) {
            rowsum[i]  += __shfl_xor(rowsum[i],  mask, 64);
            oacc[i][0] += __shfl_xor(oacc[i][0], mask, 64);
            oacc[i][1] += __shfl_xor(oacc[i][1], mask, 64);
            oacc[i][2] += __shfl_xor(oacc[i][2], mask, 64);
        }
    }

    if (cg == 0) {
        #pragma unroll
        for (int i = 0; i < 4; ++i) {
            int n = n0 + 4 * r + i;
            float inv = 1.f / rowsum[i];
            int gy = by + (n >> 5), gx = bx + (n & 31);
            out[(0 * IMH + gy) * IMW + gx] = oacc[i][0] * inv;
            out[(1 * IMH + gy) * IMW + gx] = oacc[i][1] * inv;
            out[(2 * IMH + gy) * IMW + gx] = oacc[i][2] * inv;
        }
    }
}

extern "C" void kernel_launch(void* const* d_in, const int* in_sizes, int n_in,
                              void* d_out, int out_size, void* d_ws, size_t ws_size,
                              hipStream_t stream) {
    const float* img = (const float*)d_in[0];
    float* out = (float*)d_out;
    dim3 grid(NPIX / NBLK, (IMH / TS) * (IMW / TS));   // (16, 100)
    nlm_kernel<<<grid, 256, 0, stream>>>(img, out);
}

// Round 2
// 384.299 us; speedup vs baseline: 1.0620x; 1.0620x over previous
//
#include <hip/hip_runtime.h>
#include <math.h>

#define TS   32      // tile side
#define PT   36      // padded tile side
#define NPIX 1024    // pixels per tile
#define DF   72      // real feature dim: 3 ch * 24 non-center offsets
#define KP   96      // K padded to 3 MFMA k-steps of 32
#define RS   104     // frag-array row stride in ushorts (208 B = 52 words: 2-way, free)
#define NBLK 64      // rows per workgroup (4 waves x 16)
#define MBLK 64      // cols per m-chunk
#define IMH  320
#define IMW  320
#define NTW  10      // tiles per image row

typedef __attribute__((ext_vector_type(8))) short bf16x8;  // 8 bf16 = 4 VGPRs
typedef __attribute__((ext_vector_type(4))) float f32x4;   // MFMA C/D

__global__ __launch_bounds__(256, 2)
void nlm_mfma_kernel(const float* __restrict__ img, float* __restrict__ out)
{
    __shared__ float P[3][PT][PT];                       // 15552 B
    __shared__ float sqf[NPIX];                          // 4096 B
    __shared__ int   ofs[KP];                            // 384 B, k -> P element offset
    __shared__ __align__(16) unsigned short Ahi[NBLK][RS];  // 13312 B each
    __shared__ __align__(16) unsigned short Alo[NBLK][RS];
    __shared__ __align__(16) unsigned short Bhi[MBLK][RS];
    __shared__ __align__(16) unsigned short Blo[MBLK][RS];
    // total ~73.3 KB -> 2 blocks/CU

    const int tid  = threadIdx.x;
    const int lane = tid & 63;
    const int wv   = tid >> 6;            // wave 0..3, owns rows 16*wv..16*wv+15
    const int tile = blockIdx.y;          // 0..99
    const int n0   = blockIdx.x * NBLK;
    const int by   = (tile / NTW) * TS;
    const int bx   = (tile % NTW) * TS;
    const float* Pf = &P[0][0][0];

    // ---- stage padded tile (edge-replicate) + ofs table
    for (int idx = tid; idx < 3 * PT * PT; idx += 256) {
        int c   = idx / (PT * PT);
        int rem = idx - c * (PT * PT);
        int y   = rem / PT;
        int x   = rem - y * PT;
        int iy  = min(max(y - 2, 0), TS - 1);
        int ix  = min(max(x - 2, 0), TS - 1);
        P[c][y][x] = img[(c * IMH + by + iy) * IMW + bx + ix];
    }
    if (tid < KP) {
        int k = tid, v = 0;
        if (k < DF) {
            int c  = k / 24;
            int o  = k - c * 24;
            int kk = o + (o >= 12);         // skip center patch index 12
            int i  = kk / 5, j = kk - (kk / 5) * 5;
            v = c * PT * PT + i * PT + j;
        }
        ofs[k] = v;
    }
    __syncthreads();

    // ---- fp32 squared feature norms
    for (int m = tid; m < NPIX; m += 256) {
        int my = m >> 5, mx = m & 31;
        float s = 0.f;
        #pragma unroll
        for (int k = 0; k < 25; ++k) {
            if (k == 12) continue;
            int i = k / 5, j = k - (k / 5) * 5;
            float v0 = P[0][my + i][mx + j];
            float v1 = P[1][my + i][mx + j];
            float v2 = P[2][my + i][mx + j];
            s = fmaf(v0, v0, s); s = fmaf(v1, v1, s); s = fmaf(v2, v2, s);
        }
        sqf[m] = s;
    }

    // ---- stage A features, split fp32 -> bf16 hi + bf16 lo (truncation split)
    for (int idx = tid; idx < NBLK * KP; idx += 256) {
        int r = idx / KP;
        int k = idx - r * KP;
        int n = n0 + r;
        unsigned short h = 0, l = 0;
        if (k < DF) {
            int rowbase = (n >> 5) * PT + (n & 31);
            float f = Pf[rowbase + ofs[k]];
            unsigned int u  = __float_as_uint(f);
            unsigned int hb = u & 0xffff0000u;
            float lf = f - __uint_as_float(hb);
            h = (unsigned short)(hb >> 16);
            l = (unsigned short)(__float_as_uint(lf) >> 16);
        }
        Ahi[r][k] = h;
        Alo[r][k] = l;
    }
    __syncthreads();

    // ---- A fragments held in registers for the whole m-loop
    bf16x8 aH[3], aL[3];
    {
        int row = 16 * wv + (lane & 15);
        #pragma unroll
        for (int ks = 0; ks < 3; ++ks) {
            int kk = ks * 32 + (lane >> 4) * 8;
            aH[ks] = *(const bf16x8*)&Ahi[row][kk];
            aL[ks] = *(const bf16x8*)&Alo[row][kk];
        }
    }
    const int nrow0 = n0 + 16 * wv + (lane >> 4) * 4;  // first of this lane's 4 rows
    float sqn[4];
    #pragma unroll
    for (int i = 0; i < 4; ++i) sqn[i] = sqf[nrow0 + i];

    float rowsum[4] = {0.f, 0.f, 0.f, 0.f};
    float oacc[4][3] = {};

    for (int mb = 0; mb < NPIX / MBLK; ++mb) {
        const int m0 = mb * MBLK;

        // stage B features for this 64-col chunk
        for (int idx = tid; idx < MBLK * KP; idx += 256) {
            int r = idx / KP;
            int k = idx - r * KP;
            int m = m0 + r;
            unsigned short h = 0, l = 0;
            if (k < DF) {
                int rowbase = (m >> 5) * PT + (m & 31);
                float f = Pf[rowbase + ofs[k]];
                unsigned int u  = __float_as_uint(f);
                unsigned int hb = u & 0xffff0000u;
                float lf = f - __uint_as_float(hb);
                h = (unsigned short)(hb >> 16);
                l = (unsigned short)(__float_as_uint(lf) >> 16);
            }
            Bhi[r][k] = h;
            Blo[r][k] = l;
        }
        __syncthreads();

        #pragma unroll
        for (int mp = 0; mp < 2; ++mp) {   // two passes of 2 m-tiles each
            bf16x8 b0H[3], b0L[3], b1H[3], b1L[3];
            {
                int r0 = (2 * mp) * 16 + (lane & 15);
                int r1 = (2 * mp + 1) * 16 + (lane & 15);
                #pragma unroll
                for (int ks = 0; ks < 3; ++ks) {
                    int kk = ks * 32 + (lane >> 4) * 8;
                    b0H[ks] = *(const bf16x8*)&Bhi[r0][kk];
                    b0L[ks] = *(const bf16x8*)&Blo[r0][kk];
                    b1H[ks] = *(const bf16x8*)&Bhi[r1][kk];
                    b1L[ks] = *(const bf16x8*)&Blo[r1][kk];
                }
            }
            f32x4 C0 = {0.f, 0.f, 0.f, 0.f};
            f32x4 C1 = {0.f, 0.f, 0.f, 0.f};
            #pragma unroll
            for (int ks = 0; ks < 3; ++ks) {
                C0 = __builtin_amdgcn_mfma_f32_16x16x32_bf16(aH[ks], b0H[ks], C0, 0, 0, 0);
                C1 = __builtin_amdgcn_mfma_f32_16x16x32_bf16(aH[ks], b1H[ks], C1, 0, 0, 0);
                C0 = __builtin_amdgcn_mfma_f32_16x16x32_bf16(aH[ks], b0L[ks], C0, 0, 0, 0);
                C1 = __builtin_amdgcn_mfma_f32_16x16x32_bf16(aH[ks], b1L[ks], C1, 0, 0, 0);
                C0 = __builtin_amdgcn_mfma_f32_16x16x32_bf16(aL[ks], b0H[ks], C0, 0, 0, 0);
                C1 = __builtin_amdgcn_mfma_f32_16x16x32_bf16(aL[ks], b1H[ks], C1, 0, 0, 0);
            }
            // fused epilogue for both m-tiles
            #pragma unroll
            for (int t = 0; t < 2; ++t) {
                f32x4 C = t ? C1 : C0;
                int m  = m0 + (2 * mp + t) * 16 + (lane & 15);
                float sm = sqf[m];
                int my = m >> 5, mx = m & 31;
                float y0 = P[0][my + 2][mx + 2];
                float y1 = P[1][my + 2][mx + 2];
                float y2 = P[2][my + 2][mx + 2];
                #pragma unroll
                for (int i = 0; i < 4; ++i) {
                    float d2   = fmaxf(sqn[i] + sm - 2.0f * C[i], 0.f);
                    float dens = __expf(-sqrtf(d2));
                    if (m == nrow0 + i) dens = 0.f;   // diagonal excluded
                    rowsum[i] += dens;
                    oacc[i][0] = fmaf(dens, y0, oacc[i][0]);
                    oacc[i][1] = fmaf(dens, y1, oacc[i][1]);
                    oacc[i][2] = fmaf(dens, y2, oacc[i][2]);
                }
            }
        }
        __syncthreads();   // before next chunk overwrites Bhi/Blo
    }

    // ---- reduce over the 16 lanes sharing the same row set (same lane>>4)
    #pragma unroll
    for (int mask = 1; mask < 16; mask <<= 1) {
        #pragma unroll
        for (int i = 0; i < 4; ++i) {
            rowsum[i]  += __shfl_xor(rowsum[i],  mask, 64);
            oacc[i][0] += __shfl_xor(oacc[i][0], mask, 64);
            oacc[i][1] += __shfl_xor(oacc[i][1], mask, 64);
            oacc[i][2] += __shfl_xor(oacc[i][2], mask, 64);
        }
    }
    if ((lane & 15) == 0) {
        #pragma unroll
        for (int i = 0; i < 4; ++i) {
            int n = nrow0 + i;
            float inv = 1.f / rowsum[i];
            int gy = by + (n >> 5), gx = bx + (n & 31);
            out[(0 * IMH + gy) * IMW + gx] = oacc[i][0] * inv;
            out[(1 * IMH + gy) * IMW + gx] = oacc[i][1] * inv;
            out[(2 * IMH + gy) * IMW + gx] = oacc[i][2] * inv;
        }
    }
}

extern "C" void kernel_launch(void* const* d_in, const int* in_sizes, int n_in,
                              void* d_out, int out_size, void* d_ws, size_t ws_size,
                              hipStream_t stream) {
    const float* img = (const float*)d_in[0];
    float* out = (float*)d_out;
    dim3 grid(NPIX / NBLK, (IMH / TS) * (IMW / TS));   // (16, 100)
    nlm_mfma_kernel<<<grid, 256, 0, stream>>>(img, out);
}

// Round 3
// 248.622 us; speedup vs baseline: 1.6415x; 1.5457x over previous
//
#include <hip/hip_runtime.h>
#include <math.h>

#define TS   32
#define PT   36
#define NPIX 1024
#define DF   72      // real feature dim
#define KP   96      // padded K: 3 MFMA k-steps of 32
#define IMH  320
#define IMW  320
#define NTW  10
#define NTILE 100

// ws layout: Fhi [100][12288] x 16B | Flo same | Sq [100][1024] f32
#define F_UNITS_PER_TILE 12288           // 64 rt * 3 ks * 4 c * 16 rows
#define FHI_BYTES (NTILE * F_UNITS_PER_TILE * 16)   // 19,660,800
#define SQ_OFF    (2 * FHI_BYTES)                   // 39,321,600

typedef __attribute__((ext_vector_type(8))) short bf16x8;   // MFMA A/B frag
typedef __attribute__((ext_vector_type(8))) unsigned short u16x8;
typedef __attribute__((ext_vector_type(4))) float f32x4;    // MFMA C/D

// ---------------- kernel A: per-tile feature build + split + sqf ----------
__global__ __launch_bounds__(256)
void nlm_feat_kernel(const float* __restrict__ img,
                     u16x8* __restrict__ Fhi, u16x8* __restrict__ Flo,
                     float* __restrict__ Sq)
{
    __shared__ float P[3][PT][PT];
    __shared__ int   ofs[KP];
    const int tid  = threadIdx.x;
    const int tile = blockIdx.x;
    const int by   = (tile / NTW) * TS;
    const int bx   = (tile % NTW) * TS;
    const float* Pf = &P[0][0][0];

    for (int idx = tid; idx < 3 * PT * PT; idx += 256) {
        int c = idx / (PT * PT);
        int rem = idx - c * (PT * PT);
        int y = rem / PT, x = rem - (rem / PT) * PT;
        int iy = min(max(y - 2, 0), TS - 1);
        int ix = min(max(x - 2, 0), TS - 1);
        P[c][y][x] = img[(c * IMH + by + iy) * IMW + bx + ix];
    }
    if (tid < KP) {
        int k = tid, v = 0;
        if (k < DF) {
            int c = k / 24, o = k - c * 24;
            int kk = o + (o >= 12);
            int i = kk / 5, j = kk - (kk / 5) * 5;
            v = c * PT * PT + i * PT + j;
        }
        ofs[k] = v;
    }
    __syncthreads();

    // squared feature norms (fp32, consistent with hi+lo reconstruction)
    for (int m = tid; m < NPIX; m += 256) {
        int my = m >> 5, mx = m & 31;
        float s = 0.f;
        #pragma unroll
        for (int k = 0; k < 25; ++k) {
            if (k == 12) continue;
            int i = k / 5, j = k - (k / 5) * 5;
            float v0 = P[0][my + i][mx + j];
            float v1 = P[1][my + i][mx + j];
            float v2 = P[2][my + i][mx + j];
            s = fmaf(v0, v0, s); s = fmaf(v1, v1, s); s = fmaf(v2, v2, s);
        }
        Sq[tile * NPIX + m] = s;
    }

    // features, split, fragment-swizzled store:
    // unit u = (rt*3+ks)*64 + c*16 + row  holds k = ks*32+c*8+(0..7) of pixel rt*16+row
    for (int u = tid; u < F_UNITS_PER_TILE; u += 256) {
        int row  = u & 15;
        int c    = (u >> 4) & 3;
        int rks  = u >> 6;           // rt*3 + ks
        int ks   = rks - (rks / 3) * 3;
        int rt   = rks / 3;
        int r    = rt * 16 + row;
        int base = (r >> 5) * PT + (r & 31);
        u16x8 h, l;
        #pragma unroll
        for (int j = 0; j < 8; ++j) {
            int k = ks * 32 + c * 8 + j;
            unsigned short hs = 0, ls = 0;
            if (k < DF) {
                float f = Pf[base + ofs[k]];
                unsigned int uu = __float_as_uint(f);
                unsigned int hb = uu & 0xffff0000u;
                float lf = f - __uint_as_float(hb);
                hs = (unsigned short)(hb >> 16);
                ls = (unsigned short)(__float_as_uint(lf) >> 16);
            }
            h[j] = hs; l[j] = ls;
        }
        Fhi[tile * F_UNITS_PER_TILE + u] = h;
        Flo[tile * F_UNITS_PER_TILE + u] = l;
    }
}

// ---------------- kernel B: barrier-free MFMA GEMM + fused epilogue -------
__global__ __launch_bounds__(256, 3)
void nlm_gemm_kernel(const float* __restrict__ img,
                     const bf16x8* __restrict__ Fhi, const bf16x8* __restrict__ Flo,
                     const float* __restrict__ Sq, float* __restrict__ out)
{
    const int tid  = threadIdx.x;
    const int lane = tid & 63;
    const int wv   = tid >> 6;
    const int tile = blockIdx.y;
    const int by   = (tile / NTW) * TS;
    const int bx   = (tile % NTW) * TS;
    const int rtA  = blockIdx.x * 8 + 2 * wv;    // wave owns row-tiles rtA, rtA+1
    const int quad = lane >> 4;
    const int col  = lane & 15;

    const bf16x8* FHt = Fhi + tile * F_UNITS_PER_TILE;
    const bf16x8* FLt = Flo + tile * F_UNITS_PER_TILE;
    const float*  Sqt = Sq + tile * NPIX;

    // A fragments for 2 row-tiles, hi+lo, 3 k-steps — held in regs throughout
    bf16x8 aH[2][3], aL[2][3];
    #pragma unroll
    for (int t = 0; t < 2; ++t)
        #pragma unroll
        for (int ks = 0; ks < 3; ++ks) {
            int u = ((rtA + t) * 3 + ks) * 64 + lane;
            aH[t][ks] = FHt[u];
            aL[t][ks] = FLt[u];
        }

    float sqn[2][4];
    #pragma unroll
    for (int t = 0; t < 2; ++t)
        #pragma unroll
        for (int i = 0; i < 4; ++i)
            sqn[t][i] = Sqt[(rtA + t) * 16 + quad * 4 + i];

    float rowsum[2][4] = {};
    float oacc[2][4][3] = {};

    for (int mt = 0; mt < 64; ++mt) {
        bf16x8 bH[3], bL[3];
        #pragma unroll
        for (int ks = 0; ks < 3; ++ks) {
            int u = (mt * 3 + ks) * 64 + lane;
            bH[ks] = FHt[u];
            bL[ks] = FLt[u];
        }
        f32x4 C0 = {0.f, 0.f, 0.f, 0.f};
        f32x4 C1 = {0.f, 0.f, 0.f, 0.f};
        #pragma unroll
        for (int ks = 0; ks < 3; ++ks) {
            C0 = __builtin_amdgcn_mfma_f32_16x16x32_bf16(aH[0][ks], bH[ks], C0, 0, 0, 0);
            C1 = __builtin_amdgcn_mfma_f32_16x16x32_bf16(aH[1][ks], bH[ks], C1, 0, 0, 0);
            C0 = __builtin_amdgcn_mfma_f32_16x16x32_bf16(aH[0][ks], bL[ks], C0, 0, 0, 0);
            C1 = __builtin_amdgcn_mfma_f32_16x16x32_bf16(aH[1][ks], bL[ks], C1, 0, 0, 0);
            C0 = __builtin_amdgcn_mfma_f32_16x16x32_bf16(aL[0][ks], bH[ks], C0, 0, 0, 0);
            C1 = __builtin_amdgcn_mfma_f32_16x16x32_bf16(aL[1][ks], bH[ks], C1, 0, 0, 0);
        }
        int m  = mt * 16 + col;
        float sm = Sqt[m];
        int my = m >> 5, mx = m & 31;
        float y0 = img[(0 * IMH + by + my) * IMW + bx + mx];
        float y1 = img[(1 * IMH + by + my) * IMW + bx + mx];
        float y2 = img[(2 * IMH + by + my) * IMW + bx + mx];
        #pragma unroll
        for (int t = 0; t < 2; ++t) {
            f32x4 C = t ? C1 : C0;
            int nb = (rtA + t) * 16 + quad * 4;
            #pragma unroll
            for (int i = 0; i < 4; ++i) {
                float d2   = fmaxf(sqn[t][i] + sm - 2.0f * C[i], 0.f);
                float dens = __expf(-sqrtf(d2));
                if (m == nb + i) dens = 0.f;
                rowsum[t][i] += dens;
                oacc[t][i][0] = fmaf(dens, y0, oacc[t][i][0]);
                oacc[t][i][1] = fmaf(dens, y1, oacc[t][i][1]);
                oacc[t][i][2] = fmaf(dens, y2, oacc[t][i][2]);
            }
        }
    }

    // reduce across the 16 column lanes (xor on low 4 lane bits keeps quad fixed)
    #pragma unroll
    for (int mask = 1; mask < 16; mask <<= 1)
        #pragma unroll
        for (int t = 0; t < 2; ++t)
            #pragma unroll
            for (int i = 0; i < 4; ++i) {
                rowsum[t][i]  += __shfl_xor(rowsum[t][i],  mask, 64);
                oacc[t][i][0] += __shfl_xor(oacc[t][i][0], mask, 64);
                oacc[t][i][1] += __shfl_xor(oacc[t][i][1], mask, 64);
                oacc[t][i][2] += __shfl_xor(oacc[t][i][2], mask, 64);
            }

    if (col == 0) {
        #pragma unroll
        for (int t = 0; t < 2; ++t)
            #pragma unroll
            for (int i = 0; i < 4; ++i) {
                int n = (rtA + t) * 16 + quad * 4 + i;
                float inv = 1.f / rowsum[t][i];
                int gy = by + (n >> 5), gx = bx + (n & 31);
                out[(0 * IMH + gy) * IMW + gx] = oacc[t][i][0] * inv;
                out[(1 * IMH + gy) * IMW + gx] = oacc[t][i][1] * inv;
                out[(2 * IMH + gy) * IMW + gx] = oacc[t][i][2] * inv;
            }
    }
}

extern "C" void kernel_launch(void* const* d_in, const int* in_sizes, int n_in,
                              void* d_out, int out_size, void* d_ws, size_t ws_size,
                              hipStream_t stream) {
    const float* img = (const float*)d_in[0];
    float* out = (float*)d_out;
    char* ws = (char*)d_ws;
    u16x8* Fhi = (u16x8*)ws;
    u16x8* Flo = (u16x8*)(ws + FHI_BYTES);
    float* Sq  = (float*)(ws + SQ_OFF);

    nlm_feat_kernel<<<NTILE, 256, 0, stream>>>(img, Fhi, Flo, Sq);
    dim3 grid(8, NTILE);   // 8 n-blocks (128 rows each) x 100 tiles
    nlm_gemm_kernel<<<grid, 256, 0, stream>>>(img, (const bf16x8*)Fhi,
                                              (const bf16x8*)Flo, Sq, out);
}

// Round 5
// 176.433 us; speedup vs baseline: 2.3132x; 1.4092x over previous
//
#include <hip/hip_runtime.h>
#include <math.h>

#define TS   32
#define PT   36
#define NPIX 1024
#define DF   72      // real feature dim
#define KP   96      // padded K: 3 MFMA k-steps of 32
#define IMH  320
#define IMW  320
#define NTW  10
#define NTILE 100

// ws layout (identical footprint to R3, proven): Fhi | Flo | Sq
#define F_UNITS_PER_TILE 12288           // 64 rt * 3 ks * 4 c * 16 rows
#define FHI_BYTES (NTILE * F_UNITS_PER_TILE * 16)   // 19,660,800
#define SQ_OFF    (2 * FHI_BYTES)                   // 39,321,600 (+409,600 = 39.73 MB)

typedef __attribute__((ext_vector_type(8))) short bf16x8;   // MFMA A/B frag
typedef __attribute__((ext_vector_type(8))) unsigned short u16x8;
typedef __attribute__((ext_vector_type(4))) float f32x4;    // MFMA C/D

// ---------------- kernel A: per-tile feature build + split + sqf ----------
// grid (4 parts, 100 tiles)
__global__ __launch_bounds__(256)
void nlm_feat_kernel(const float* __restrict__ img,
                     u16x8* __restrict__ Fhi, u16x8* __restrict__ Flo,
                     float* __restrict__ Sq)
{
    __shared__ float P[3][PT][PT];
    __shared__ int   ofs[KP];
    const int tid  = threadIdx.x;
    const int part = blockIdx.x;    // 0..3
    const int tile = blockIdx.y;
    const int by   = (tile / NTW) * TS;
    const int bx   = (tile % NTW) * TS;
    const float* Pf = &P[0][0][0];

    for (int idx = tid; idx < 3 * PT * PT; idx += 256) {
        int c = idx / (PT * PT);
        int rem = idx - c * (PT * PT);
        int y = rem / PT, x = rem - (rem / PT) * PT;
        int iy = min(max(y - 2, 0), TS - 1);
        int ix = min(max(x - 2, 0), TS - 1);
        P[c][y][x] = img[(c * IMH + by + iy) * IMW + bx + ix];
    }
    if (tid < KP) {
        int k = tid, v = 0;
        if (k < DF) {
            int c = k / 24, o = k - c * 24;
            int kk = o + (o >= 12);
            int i = kk / 5, j = kk - (kk / 5) * 5;
            v = c * PT * PT + i * PT + j;
        }
        ofs[k] = v;
    }
    __syncthreads();

    // squared feature norms for this part's 256 pixels
    {
        int m = part * 256 + tid;
        int my = m >> 5, mx = m & 31;
        float s = 0.f;
        #pragma unroll
        for (int k = 0; k < 25; ++k) {
            if (k == 12) continue;
            int i = k / 5, j = k - (k / 5) * 5;
            float v0 = P[0][my + i][mx + j];
            float v1 = P[1][my + i][mx + j];
            float v2 = P[2][my + i][mx + j];
            s = fmaf(v0, v0, s); s = fmaf(v1, v1, s); s = fmaf(v2, v2, s);
        }
        Sq[tile * NPIX + m] = s;
    }

    // features, split fp32 -> bf16 hi/lo, fragment-swizzled store (quarter)
    for (int u = part * 3072 + tid; u < (part + 1) * 3072; u += 256) {
        int row  = u & 15;
        int c    = (u >> 4) & 3;
        int rks  = u >> 6;           // rt*3 + ks
        int ks   = rks - (rks / 3) * 3;
        int rt   = rks / 3;
        int r    = rt * 16 + row;
        int base = (r >> 5) * PT + (r & 31);
        u16x8 h, l;
        #pragma unroll
        for (int j = 0; j < 8; ++j) {
            int k = ks * 32 + c * 8 + j;
            unsigned short hs = 0, ls = 0;
            if (k < DF) {
                float f = Pf[base + ofs[k]];
                unsigned int uu = __float_as_uint(f);
                unsigned int hb = uu & 0xffff0000u;
                float lf = f - __uint_as_float(hb);
                hs = (unsigned short)(hb >> 16);
                ls = (unsigned short)(__float_as_uint(lf) >> 16);
            }
            h[j] = hs; l[j] = ls;
        }
        Fhi[tile * F_UNITS_PER_TILE + u] = h;
        Flo[tile * F_UNITS_PER_TILE + u] = l;
    }
}

// ---------------- kernel B: MFMA GEMM, m-split across waves ---------------
// grid (32, 100): block owns 32 rows (2 row-tiles); wave wv sweeps 16 mt.
// waves_per_eu(2,3): don't chase >3 waves/EU -> keep A-frags resident.
__global__ __launch_bounds__(256)
__attribute__((amdgpu_waves_per_eu(2, 3)))
void nlm_gemm_kernel(const float* __restrict__ img,
                     const bf16x8* __restrict__ Fhi, const bf16x8* __restrict__ Flo,
                     const float* __restrict__ Sq, float* __restrict__ out)
{
    __shared__ float red[4][32][4];   // cross-wave partials
    const int tid  = threadIdx.x;
    const int lane = tid & 63;
    const int wv   = tid >> 6;
    const int tile = blockIdx.y;
    const int by   = (tile / NTW) * TS;
    const int bx   = (tile % NTW) * TS;
    const int rtA  = blockIdx.x * 2;     // block's 2 row-tiles
    const int quad = lane >> 4;
    const int col  = lane & 15;

    const bf16x8* FHt = Fhi + tile * F_UNITS_PER_TILE;
    const bf16x8* FLt = Flo + tile * F_UNITS_PER_TILE;
    const float*  Sqt = Sq + tile * NPIX;

    // A fragments (2 row-tiles, hi+lo, 3 k-steps) — loop-invariant
    bf16x8 aH[2][3], aL[2][3];
    #pragma unroll
    for (int t = 0; t < 2; ++t)
        #pragma unroll
        for (int ks = 0; ks < 3; ++ks) {
            int u = ((rtA + t) * 3 + ks) * 64 + lane;
            aH[t][ks] = FHt[u];
            aL[t][ks] = FLt[u];
        }

    float sqn[2][4];
    #pragma unroll
    for (int t = 0; t < 2; ++t)
        #pragma unroll
        for (int i = 0; i < 4; ++i)
            sqn[t][i] = Sqt[(rtA + t) * 16 + quad * 4 + i];

    float rowsum[2][4] = {};
    float oacc[2][4][3] = {};

    #pragma unroll 2
    for (int it = 0; it < 16; ++it) {
        const int mt = wv * 16 + it;       // this wave's m-tile
        bf16x8 bH[3], bL[3];
        #pragma unroll
        for (int ks = 0; ks < 3; ++ks) {
            int u = (mt * 3 + ks) * 64 + lane;
            bH[ks] = FHt[u];
            bL[ks] = FLt[u];
        }
        const int m  = mt * 16 + col;
        float sm = Sqt[m];
        int my = m >> 5, mx = m & 31;
        float y0 = img[(0 * IMH + by + my) * IMW + bx + mx];
        float y1 = img[(1 * IMH + by + my) * IMW + bx + mx];
        float y2 = img[(2 * IMH + by + my) * IMW + bx + mx];

        f32x4 C0 = {0.f, 0.f, 0.f, 0.f};
        f32x4 C1 = {0.f, 0.f, 0.f, 0.f};
        #pragma unroll
        for (int ks = 0; ks < 3; ++ks) {
            C0 = __builtin_amdgcn_mfma_f32_16x16x32_bf16(aH[0][ks], bH[ks], C0, 0, 0, 0);
            C1 = __builtin_amdgcn_mfma_f32_16x16x32_bf16(aH[1][ks], bH[ks], C1, 0, 0, 0);
            C0 = __builtin_amdgcn_mfma_f32_16x16x32_bf16(aH[0][ks], bL[ks], C0, 0, 0, 0);
            C1 = __builtin_amdgcn_mfma_f32_16x16x32_bf16(aH[1][ks], bL[ks], C1, 0, 0, 0);
            C0 = __builtin_amdgcn_mfma_f32_16x16x32_bf16(aL[0][ks], bH[ks], C0, 0, 0, 0);
            C1 = __builtin_amdgcn_mfma_f32_16x16x32_bf16(aL[1][ks], bH[ks], C1, 0, 0, 0);
        }
        #pragma unroll
        for (int t = 0; t < 2; ++t) {
            f32x4 C = t ? C1 : C0;
            int nb = (rtA + t) * 16 + quad * 4;
            #pragma unroll
            for (int i = 0; i < 4; ++i) {
                float d2   = fmaxf(sqn[t][i] + sm - 2.0f * C[i], 0.f);
                float dens = __expf(-sqrtf(d2));
                if (m == nb + i) dens = 0.f;
                rowsum[t][i] += dens;
                oacc[t][i][0] = fmaf(dens, y0, oacc[t][i][0]);
                oacc[t][i][1] = fmaf(dens, y1, oacc[t][i][1]);
                oacc[t][i][2] = fmaf(dens, y2, oacc[t][i][2]);
            }
        }
    }

    // in-wave reduce over the 16 column lanes
    #pragma unroll
    for (int mask = 1; mask < 16; mask <<= 1)
        #pragma unroll
        for (int t = 0; t < 2; ++t)
            #pragma unroll
            for (int i = 0; i < 4; ++i) {
                rowsum[t][i]  += __shfl_xor(rowsum[t][i],  mask, 64);
                oacc[t][i][0] += __shfl_xor(oacc[t][i][0], mask, 64);
                oacc[t][i][1] += __shfl_xor(oacc[t][i][1], mask, 64);
                oacc[t][i][2] += __shfl_xor(oacc[t][i][2], mask, 64);
            }

    if (col == 0) {
        #pragma unroll
        for (int t = 0; t < 2; ++t)
            #pragma unroll
            for (int i = 0; i < 4; ++i) {
                int lr = t * 16 + quad * 4 + i;
                red[wv][lr][0] = rowsum[t][i];
                red[wv][lr][1] = oacc[t][i][0];
                red[wv][lr][2] = oacc[t][i][1];
                red[wv][lr][3] = oacc[t][i][2];
            }
    }
    __syncthreads();

    if (tid < 32) {
        float s = 0.f, o0 = 0.f, o1 = 0.f, o2 = 0.f;
        #pragma unroll
        for (int w = 0; w < 4; ++w) {
            s  += red[w][tid][0];
            o0 += red[w][tid][1];
            o1 += red[w][tid][2];
            o2 += red[w][tid][3];
        }
        int n = rtA * 16 + tid;
        float inv = 1.f / s;
        int gy = by + (n >> 5), gx = bx + (n & 31);
        out[(0 * IMH + gy) * IMW + gx] = o0 * inv;
        out[(1 * IMH + gy) * IMW + gx] = o1 * inv;
        out[(2 * IMH + gy) * IMW + gx] = o2 * inv;
    }
}

extern "C" void kernel_launch(void* const* d_in, const int* in_sizes, int n_in,
                              void* d_out, int out_size, void* d_ws, size_t ws_size,
                              hipStream_t stream) {
    const float* img = (const float*)d_in[0];
    float* out = (float*)d_out;
    char* ws = (char*)d_ws;
    u16x8* Fhi = (u16x8*)ws;
    u16x8* Flo = (u16x8*)(ws + FHI_BYTES);
    float* Sq  = (float*)(ws + SQ_OFF);

    dim3 fgrid(4, NTILE);
    nlm_feat_kernel<<<fgrid, 256, 0, stream>>>(img, Fhi, Flo, Sq);
    dim3 grid(32, NTILE);   // 32 row-groups x 100 tiles, m split across waves
    nlm_gemm_kernel<<<grid, 256, 0, stream>>>(img, (const bf16x8*)Fhi,
                                              (const bf16x8*)Flo, Sq, out);
}

// Round 6
// 152.275 us; speedup vs baseline: 2.6802x; 1.1586x over previous
//
#include <hip/hip_runtime.h>
#include <math.h>

#define TS   32
#define PT   36
#define NPIX 1024
#define DF   72      // real feature dim
#define KP   96      // padded K: 3 MFMA k-steps of 32
#define IMH  320
#define IMW  320
#define NTW  10
#define NTILE 100

// ws layout (identical footprint to R3/R5, proven): Fhi | Flo | Sq
#define F_UNITS_PER_TILE 12288           // 64 rt * 3 ks * 4 c * 16 rows
#define FHI_BYTES (NTILE * F_UNITS_PER_TILE * 16)   // 19,660,800
#define SQ_OFF    (2 * FHI_BYTES)                   // 39,321,600 (+409,600 = 39.73 MB)

typedef __attribute__((ext_vector_type(8))) short bf16x8;   // MFMA A/B frag
typedef __attribute__((ext_vector_type(8))) unsigned short u16x8;
typedef __attribute__((ext_vector_type(4))) float f32x4;    // MFMA C/D

// ---------------- kernel A: per-tile feature build + split + sqf ----------
// grid (4 parts, 100 tiles)
__global__ __launch_bounds__(256)
void nlm_feat_kernel(const float* __restrict__ img,
                     u16x8* __restrict__ Fhi, u16x8* __restrict__ Flo,
                     float* __restrict__ Sq)
{
    __shared__ float P[3][PT][PT];
    __shared__ int   ofs[KP];
    const int tid  = threadIdx.x;
    const int part = blockIdx.x;    // 0..3
    const int tile = blockIdx.y;
    const int by   = (tile / NTW) * TS;
    const int bx   = (tile % NTW) * TS;
    const float* Pf = &P[0][0][0];

    for (int idx = tid; idx < 3 * PT * PT; idx += 256) {
        int c = idx / (PT * PT);
        int rem = idx - c * (PT * PT);
        int y = rem / PT, x = rem - (rem / PT) * PT;
        int iy = min(max(y - 2, 0), TS - 1);
        int ix = min(max(x - 2, 0), TS - 1);
        P[c][y][x] = img[(c * IMH + by + iy) * IMW + bx + ix];
    }
    if (tid < KP) {
        int k = tid, v = 0;
        if (k < DF) {
            int c = k / 24, o = k - c * 24;
            int kk = o + (o >= 12);
            int i = kk / 5, j = kk - (kk / 5) * 5;
            v = c * PT * PT + i * PT + j;
        }
        ofs[k] = v;
    }
    __syncthreads();

    // squared feature norms for this part's 256 pixels
    {
        int m = part * 256 + tid;
        int my = m >> 5, mx = m & 31;
        float s = 0.f;
        #pragma unroll
        for (int k = 0; k < 25; ++k) {
            if (k == 12) continue;
            int i = k / 5, j = k - (k / 5) * 5;
            float v0 = P[0][my + i][mx + j];
            float v1 = P[1][my + i][mx + j];
            float v2 = P[2][my + i][mx + j];
            s = fmaf(v0, v0, s); s = fmaf(v1, v1, s); s = fmaf(v2, v2, s);
        }
        Sq[tile * NPIX + m] = s;
    }

    // features, split fp32 -> bf16 hi/lo, fragment-swizzled store (quarter)
    for (int u = part * 3072 + tid; u < (part + 1) * 3072; u += 256) {
        int row  = u & 15;
        int c    = (u >> 4) & 3;
        int rks  = u >> 6;           // rt*3 + ks
        int ks   = rks - (rks / 3) * 3;
        int rt   = rks / 3;
        int r    = rt * 16 + row;
        int base = (r >> 5) * PT + (r & 31);
        u16x8 h, l;
        #pragma unroll
        for (int j = 0; j < 8; ++j) {
            int k = ks * 32 + c * 8 + j;
            unsigned short hs = 0, ls = 0;
            if (k < DF) {
                float f = Pf[base + ofs[k]];
                unsigned int uu = __float_as_uint(f);
                unsigned int hb = uu & 0xffff0000u;
                float lf = f - __uint_as_float(hb);
                hs = (unsigned short)(hb >> 16);
                ls = (unsigned short)(__float_as_uint(lf) >> 16);
            }
            h[j] = hs; l[j] = ls;
        }
        Fhi[tile * F_UNITS_PER_TILE + u] = h;
        Flo[tile * F_UNITS_PER_TILE + u] = l;
    }
}

// ---------------- kernel B: MFMA GEMM, m-split across waves ---------------
// grid (32, 100): block owns 32 rows (2 row-tiles); wave wv sweeps 16 mt.
// waves_per_eu(3): VGPR budget ~170 so the pinned A-frags (48 VGPRs) fit
// alongside the loop body without spill.
__global__ __launch_bounds__(256)
__attribute__((amdgpu_waves_per_eu(3)))
void nlm_gemm_kernel(const float* __restrict__ img,
                     const bf16x8* __restrict__ Fhi, const bf16x8* __restrict__ Flo,
                     const float* __restrict__ Sq, float* __restrict__ out)
{
    __shared__ float red[4][32][4];   // cross-wave partials
    const int tid  = threadIdx.x;
    const int lane = tid & 63;
    const int wv   = tid >> 6;
    const int tile = blockIdx.y;
    const int by   = (tile / NTW) * TS;
    const int bx   = (tile % NTW) * TS;
    const int rtA  = blockIdx.x * 2;     // block's 2 row-tiles
    const int quad = lane >> 4;
    const int col  = lane & 15;

    const bf16x8* FHt = Fhi + tile * F_UNITS_PER_TILE;
    const bf16x8* FLt = Flo + tile * F_UNITS_PER_TILE;
    const float*  Sqt = Sq + tile * NPIX;

    // A fragments (2 row-tiles, hi+lo, 3 k-steps) — loaded ONCE, pinned below
    bf16x8 aH[2][3], aL[2][3];
    #pragma unroll
    for (int t = 0; t < 2; ++t)
        #pragma unroll
        for (int ks = 0; ks < 3; ++ks) {
            int u = ((rtA + t) * 3 + ks) * 64 + lane;
            aH[t][ks] = FHt[u];
            aL[t][ks] = FLt[u];
        }
    // Opaque barrier: forces the 12 fragments to live in VGPRs and blocks the
    // register allocator from rematerializing the loads inside the m-loop.
    asm volatile(""
        : "+v"(aH[0][0]), "+v"(aH[0][1]), "+v"(aH[0][2]),
          "+v"(aH[1][0]), "+v"(aH[1][1]), "+v"(aH[1][2]),
          "+v"(aL[0][0]), "+v"(aL[0][1]), "+v"(aL[0][2]),
          "+v"(aL[1][0]), "+v"(aL[1][1]), "+v"(aL[1][2]));

    float sqn[2][4];
    #pragma unroll
    for (int t = 0; t < 2; ++t)
        #pragma unroll
        for (int i = 0; i < 4; ++i)
            sqn[t][i] = Sqt[(rtA + t) * 16 + quad * 4 + i];

    float rowsum[2][4] = {};
    float oacc[2][4][3] = {};

    #pragma unroll 2
    for (int it = 0; it < 16; ++it) {
        const int mt = wv * 16 + it;       // this wave's m-tile
        bf16x8 bH[3], bL[3];
        #pragma unroll
        for (int ks = 0; ks < 3; ++ks) {
            int u = (mt * 3 + ks) * 64 + lane;
            bH[ks] = FHt[u];
            bL[ks] = FLt[u];
        }
        const int m  = mt * 16 + col;
        float sm = Sqt[m];
        int my = m >> 5, mx = m & 31;
        float y0 = img[(0 * IMH + by + my) * IMW + bx + mx];
        float y1 = img[(1 * IMH + by + my) * IMW + bx + mx];
        float y2 = img[(2 * IMH + by + my) * IMW + bx + mx];

        f32x4 C0 = {0.f, 0.f, 0.f, 0.f};
        f32x4 C1 = {0.f, 0.f, 0.f, 0.f};
        #pragma unroll
        for (int ks = 0; ks < 3; ++ks) {
            C0 = __builtin_amdgcn_mfma_f32_16x16x32_bf16(aH[0][ks], bH[ks], C0, 0, 0, 0);
            C1 = __builtin_amdgcn_mfma_f32_16x16x32_bf16(aH[1][ks], bH[ks], C1, 0, 0, 0);
            C0 = __builtin_amdgcn_mfma_f32_16x16x32_bf16(aH[0][ks], bL[ks], C0, 0, 0, 0);
            C1 = __builtin_amdgcn_mfma_f32_16x16x32_bf16(aH[1][ks], bL[ks], C1, 0, 0, 0);
            C0 = __builtin_amdgcn_mfma_f32_16x16x32_bf16(aL[0][ks], bH[ks], C0, 0, 0, 0);
            C1 = __builtin_amdgcn_mfma_f32_16x16x32_bf16(aL[1][ks], bH[ks], C1, 0, 0, 0);
        }
        #pragma unroll
        for (int t = 0; t < 2; ++t) {
            f32x4 C = t ? C1 : C0;
            int nb = (rtA + t) * 16 + quad * 4;
            #pragma unroll
            for (int i = 0; i < 4; ++i) {
                float d2   = fmaxf(sqn[t][i] + sm - 2.0f * C[i], 0.f);
                // raw v_sqrt_f32 (1 ulp) — avoids the IEEE-sqrt fixup sequence
                float dens = __expf(-__builtin_amdgcn_sqrtf(d2));
                if (m == nb + i) dens = 0.f;
                rowsum[t][i] += dens;
                oacc[t][i][0] = fmaf(dens, y0, oacc[t][i][0]);
                oacc[t][i][1] = fmaf(dens, y1, oacc[t][i][1]);
                oacc[t][i][2] = fmaf(dens, y2, oacc[t][i][2]);
            }
        }
    }

    // in-wave reduce over the 16 column lanes
    #pragma unroll
    for (int mask = 1; mask < 16; mask <<= 1)
        #pragma unroll
        for (int t = 0; t < 2; ++t)
            #pragma unroll
            for (int i = 0; i < 4; ++i) {
                rowsum[t][i]  += __shfl_xor(rowsum[t][i],  mask, 64);
                oacc[t][i][0] += __shfl_xor(oacc[t][i][0], mask, 64);
                oacc[t][i][1] += __shfl_xor(oacc[t][i][1], mask, 64);
                oacc[t][i][2] += __shfl_xor(oacc[t][i][2], mask, 64);
            }

    if (col == 0) {
        #pragma unroll
        for (int t = 0; t < 2; ++t)
            #pragma unroll
            for (int i = 0; i < 4; ++i) {
                int lr = t * 16 + quad * 4 + i;
                red[wv][lr][0] = rowsum[t][i];
                red[wv][lr][1] = oacc[t][i][0];
                red[wv][lr][2] = oacc[t][i][1];
                red[wv][lr][3] = oacc[t][i][2];
            }
    }
    __syncthreads();

    if (tid < 32) {
        float s = 0.f, o0 = 0.f, o1 = 0.f, o2 = 0.f;
        #pragma unroll
        for (int w = 0; w < 4; ++w) {
            s  += red[w][tid][0];
            o0 += red[w][tid][1];
            o1 += red[w][tid][2];
            o2 += red[w][tid][3];
        }
        int n = rtA * 16 + tid;
        float inv = 1.f / s;
        int gy = by + (n >> 5), gx = bx + (n & 31);
        out[(0 * IMH + gy) * IMW + gx] = o0 * inv;
        out[(1 * IMH + gy) * IMW + gx] = o1 * inv;
        out[(2 * IMH + gy) * IMW + gx] = o2 * inv;
    }
}

extern "C" void kernel_launch(void* const* d_in, const int* in_sizes, int n_in,
                              void* d_out, int out_size, void* d_ws, size_t ws_size,
                              hipStream_t stream) {
    const float* img = (const float*)d_in[0];
    float* out = (float*)d_out;
    char* ws = (char*)d_ws;
    u16x8* Fhi = (u16x8*)ws;
    u16x8* Flo = (u16x8*)(ws + FHI_BYTES);
    float* Sq  = (float*)(ws + SQ_OFF);

    dim3 fgrid(4, NTILE);
    nlm_feat_kernel<<<fgrid, 256, 0, stream>>>(img, Fhi, Flo, Sq);
    dim3 grid(32, NTILE);   // 32 row-groups x 100 tiles, m split across waves
    nlm_gemm_kernel<<<grid, 256, 0, stream>>>(img, (const bf16x8*)Fhi,
                                              (const bf16x8*)Flo, Sq, out);
}